// Round 12
// baseline (837.276 us; speedup 1.0000x reference)
//
#include <hip/hip_runtime.h>

#define NN 100000
#define EE 600000
#define DD 128
#define LL 5
#define CTROWS 5152   // 2*2*23*8*7 combined edge-feature rows
#define MBLK 1563     // psum/psq allocation rows
#define TILES 1563    // ceil(NN/64) 64-node tiles for persistent mlp
#define PBLK 256      // persistent mlp blocks (1 per CU)
#define SBLK 98       // scan blocks: 98*1024 >= NN

typedef float f32x4 __attribute__((ext_vector_type(4)));
typedef _Float16 f16x8 __attribute__((ext_vector_type(8)));
typedef _Float16 f16x4 __attribute__((ext_vector_type(4)));

// ---------------- seed: h = sum of 6 atom-feature embeddings (fp16 out) ------
__global__ __launch_bounds__(256) void seed_kernel(
    const int* __restrict__ an, const int* __restrict__ fc,
    const int* __restrict__ ct, const int* __restrict__ hy,
    const int* __restrict__ nh, const int* __restrict__ ar,
    const float* __restrict__ ean, const float* __restrict__ efc,
    const float* __restrict__ ect, const float* __restrict__ ehy,
    const float* __restrict__ enh, const float* __restrict__ ear,
    _Float16* __restrict__ h)
{
    int idx = blockIdx.x * 256 + threadIdx.x;   // NN*16 exactly
    int n = idx >> 4, q = idx & 15;
    f32x4 a0 = ((const f32x4*)(ean + an[n] * DD))[2 * q];
    f32x4 a1 = ((const f32x4*)(ean + an[n] * DD))[2 * q + 1];
    a0 += ((const f32x4*)(efc + fc[n] * DD))[2 * q];
    a1 += ((const f32x4*)(efc + fc[n] * DD))[2 * q + 1];
    a0 += ((const f32x4*)(ect + ct[n] * DD))[2 * q];
    a1 += ((const f32x4*)(ect + ct[n] * DD))[2 * q + 1];
    a0 += ((const f32x4*)(ehy + hy[n] * DD))[2 * q];
    a1 += ((const f32x4*)(ehy + hy[n] * DD))[2 * q + 1];
    a0 += ((const f32x4*)(enh + nh[n] * DD))[2 * q];
    a1 += ((const f32x4*)(enh + nh[n] * DD))[2 * q + 1];
    a0 += ((const f32x4*)(ear + ar[n] * DD))[2 * q];
    a1 += ((const f32x4*)(ear + ar[n] * DD))[2 * q + 1];
    f16x8 o;
    #pragma unroll
    for (int j = 0; j < 4; ++j) { o[j] = (_Float16)a0[j]; o[j + 4] = (_Float16)a1[j]; }
    ((f16x8*)h)[idx] = o;
}

// -------- weight convert+transpose to fp16 [n][k] + idss + dcnt zero ---------
__global__ __launch_bounds__(256) void convw_kernel(
    const float* __restrict__ w1, const float* __restrict__ w2,
    _Float16* __restrict__ w1t, _Float16* __restrict__ w2t,
    float* __restrict__ idss, int* __restrict__ dcnt)
{
    int b = blockIdx.x;
    if (b < 640) {
        int idx = b * 256 + threadIdx.x;        // 5*256*128
        int l = idx >> 15, rem = idx & 32767;
        int n = rem >> 7, k = rem & 127;
        w1t[idx] = (_Float16)w1[l * 32768 + k * 256 + n];
    } else if (b < 1280) {
        int idx = (b - 640) * 256 + threadIdx.x; // 5*128*256
        int l = idx >> 15, rem = idx & 32767;
        int n = rem >> 8, k = rem & 255;
        w2t[idx] = (_Float16)w2[l * 32768 + k * 128 + n];
    } else {
        int t = threadIdx.x;
        idss[t] = (t < 128) ? 1.0f : 0.0f;
        if (t < 8) dcnt[t] = 0;                  // per-layer done-counters
    }
}

// ---------------- CSR build: count, 3-phase scan, fill ----------------
__global__ __launch_bounds__(256) void count_kernel(const int* __restrict__ ei,
                                                    int* __restrict__ cursor)
{
    int e = blockIdx.x * 256 + threadIdx.x;
    if (e < EE) atomicAdd(&cursor[ei[EE + e]], 1);
}

__global__ __launch_bounds__(1024) void btot_kernel(const int* __restrict__ cursor,
                                                    int* __restrict__ btot)
{
    __shared__ int wsum[16];
    int tid = threadIdx.x;
    int i = blockIdx.x * 1024 + tid;
    int x = (i < NN) ? cursor[i] : 0;
    #pragma unroll
    for (int off = 1; off < 64; off <<= 1) x += __shfl_xor(x, off, 64);
    if ((tid & 63) == 0) wsum[tid >> 6] = x;
    __syncthreads();
    if (tid == 0) {
        int s = 0;
        #pragma unroll
        for (int w = 0; w < 16; ++w) s += wsum[w];
        btot[blockIdx.x] = s;
    }
}

__global__ __launch_bounds__(128) void bscan_kernel(const int* __restrict__ btot,
                                                    int* __restrict__ boff,
                                                    int* __restrict__ rowstart)
{
    __shared__ int w0;
    int t = threadIdx.x;
    int lane = t & 63, wv = t >> 6;
    int x = (t < SBLK) ? btot[t] : 0;
    int incl = x;
    #pragma unroll
    for (int off = 1; off < 64; off <<= 1) {
        int u = __shfl_up(incl, off, 64);
        if (lane >= off) incl += u;
    }
    if (wv == 0 && lane == 63) w0 = incl;
    __syncthreads();
    if (wv == 1) incl += w0;
    if (t < SBLK) boff[t] = incl - x;
    if (t == 127) rowstart[NN] = incl;   // grand total
}

__global__ __launch_bounds__(1024) void apply_kernel(const int* __restrict__ cursorin,
                                                     const int* __restrict__ boff,
                                                     int* __restrict__ rowstart,
                                                     int* __restrict__ cursor)
{
    __shared__ int wsum[16];
    int tid = threadIdx.x;
    int lane = tid & 63, wv = tid >> 6;
    int i = blockIdx.x * 1024 + tid;
    int x = (i < NN) ? cursorin[i] : 0;
    int incl = x;
    #pragma unroll
    for (int off = 1; off < 64; off <<= 1) {
        int u = __shfl_up(incl, off, 64);
        if (lane >= off) incl += u;
    }
    if (lane == 63) wsum[wv] = incl;
    __syncthreads();
    int pre = 0;
    #pragma unroll
    for (int w = 0; w < 16; ++w) pre += (w < wv) ? wsum[w] : 0;
    int excl = boff[blockIdx.x] + pre + incl - x;
    if (i < NN) { rowstart[i] = excl; cursor[i] = excl; }
}

__global__ __launch_bounds__(256) void fill_kernel(
    const int* __restrict__ ei, int* __restrict__ cursor, int* __restrict__ rec,
    const int* __restrict__ f0, const int* __restrict__ f1,
    const int* __restrict__ f2, const int* __restrict__ f3,
    const int* __restrict__ f4)
{
    int e = blockIdx.x * 256 + threadIdx.x;
    if (e >= EE) return;
    int dst = ei[EE + e];
    int p = atomicAdd(&cursor[dst], 1);
    int f = f0[e] + 2 * (f1[e] + 2 * (f2[e] + 23 * (f3[e] + 8 * f4[e])));
    rec[p] = ei[e] | (f << 17);
}

// ------------- combined edge-embedding tables, ALL 5 layers (fp16 out) -------
__global__ __launch_bounds__(256) void ctab_kernel(
    const float* __restrict__ ec, const float* __restrict__ ea,
    const float* __restrict__ eb, const float* __restrict__ ed,
    const float* __restrict__ es, _Float16* __restrict__ ctab5)
{
    int idx = blockIdx.x * 256 + threadIdx.x;   // 5*CTROWS*16 exactly (1610 blocks)
    int q = idx & 15;
    int grow = idx >> 4;                        // 0 .. 5*CTROWS
    int l = grow / CTROWS, row = grow - l * CTROWS;
    int conj = row & 1, arom = (row >> 1) & 1;
    int r2 = row >> 2;
    int bt = r2 % 23, r3 = r2 / 23;
    int bd = r3 & 7, bs = r3 >> 3;
    const float* ecl = ec + l * 3 * DD;
    const float* eal = ea + l * 3 * DD;
    const float* ebl = eb + l * 23 * DD;
    const float* edl = ed + l * 8 * DD;
    const float* esl = es + l * 7 * DD;
    f32x4 a0 = ((const f32x4*)(ecl + conj * DD))[2 * q]
             + ((const f32x4*)(eal + arom * DD))[2 * q]
             + ((const f32x4*)(ebl + bt * DD))[2 * q]
             + ((const f32x4*)(edl + bd * DD))[2 * q]
             + ((const f32x4*)(esl + bs * DD))[2 * q];
    f32x4 a1 = ((const f32x4*)(ecl + conj * DD))[2 * q + 1]
             + ((const f32x4*)(eal + arom * DD))[2 * q + 1]
             + ((const f32x4*)(ebl + bt * DD))[2 * q + 1]
             + ((const f32x4*)(edl + bd * DD))[2 * q + 1]
             + ((const f32x4*)(esl + bs * DD))[2 * q + 1];
    f16x8 o;
    #pragma unroll
    for (int j = 0; j < 4; ++j) { o[j] = (_Float16)a0[j]; o[j + 4] = (_Float16)a1[j]; }
    ((f16x8*)ctab5)[idx] = o;
}

// ---------------- gather-aggregate with fused BN(+relu), fp16 in/out ---------
// Round-8-VERIFIED version (single chain, 6250 blocks, 3-deep pipeline,
// packed-fp16 BN math + f32 widening accumulate). r11's dual-chain variant
// regressed (compiler couldn't hold 2 pipelines; occupancy halved) - reverted.
__global__ __launch_bounds__(256) void gather_bn_kernel(
    const _Float16* __restrict__ hsrc, _Float16* __restrict__ agg,
    const int* __restrict__ rowstart, const int* __restrict__ rec,
    const _Float16* __restrict__ ctab, const float* __restrict__ ss, int dorelu)
{
    int idx = blockIdx.x * 256 + threadIdx.x;   // NN*16
    int n = idx >> 4, q = idx & 15;
    f16x8 sc8, sh8, clampv;
    _Float16 cl = dorelu ? (_Float16)0.0f : (_Float16)(-60000.0f);
    #pragma unroll
    for (int j = 0; j < 8; ++j) {
        sc8[j] = (_Float16)ss[q * 8 + j];
        sh8[j] = (_Float16)ss[128 + q * 8 + j];
        clampv[j] = cl;
    }
    int p0 = rowstart[n], p1 = rowstart[n + 1];
    f16x8 x = ((const f16x8*)hsrc)[idx];
    f16x8 c0 = ((const f16x8*)ctab)[q];           // self_vec == ctab row 0
    f16x8 ts = __builtin_elementwise_max((f16x8)(x * sc8 + sh8), clampv);
    float v[8];
    #pragma unroll
    for (int j = 0; j < 8; ++j) v[j] = (float)ts[j] + (float)c0[j];

    if (p0 < p1) {
        // prologue: 2 staged rows + rec 3 ahead
        int r0 = rec[p0];
        int r1 = (p0 + 1 < p1) ? rec[p0 + 1] : r0;
        int rr2 = (p0 + 2 < p1) ? rec[p0 + 2] : r1;
        f16x8 y0 = *(const f16x8*)(hsrc + (size_t)(r0 & 0x1FFFF) * DD + q * 8);
        f16x8 e0 = *(const f16x8*)(ctab + (size_t)(((unsigned)r0) >> 17) * DD + q * 8);
        f16x8 y1 = *(const f16x8*)(hsrc + (size_t)(r1 & 0x1FFFF) * DD + q * 8);
        f16x8 e1 = *(const f16x8*)(ctab + (size_t)(((unsigned)r1) >> 17) * DD + q * 8);
        for (int p = p0; p < p1; ++p) {
            int r3 = (p + 3 < p1) ? rec[p + 3] : rr2;
            f16x8 y2 = *(const f16x8*)(hsrc + (size_t)(rr2 & 0x1FFFF) * DD + q * 8);
            f16x8 e2 = *(const f16x8*)(ctab + (size_t)(((unsigned)rr2) >> 17) * DD + q * 8);
            f16x8 t = __builtin_elementwise_max((f16x8)(y0 * sc8 + sh8), clampv);
            f16x8 u = t + e0;
            #pragma unroll
            for (int j = 0; j < 8; ++j) v[j] += (float)u[j];
            y0 = y1; e0 = e1; y1 = y2; e1 = e2; rr2 = r3;
        }
    }
    f16x8 o;
    #pragma unroll
    for (int j = 0; j < 8; ++j) o[j] = (_Float16)v[j];
    ((f16x8*)agg)[idx] = o;
}

// ---------------- fused MLP + LAST-BLOCK BN-stat reduction ----------------
// Round-8-verified persistent structure (grid=256, weights in registers,
// double-buffered hid, one barrier/tile, ba refill after last use) PLUS
// round 12: the final arriving block folds psum/psq -> ss in-kernel
// (standard last-block idiom: write partials, __threadfence, per-layer
// atomic counter; the 256th block re-reads 256x128 partials from L2 and
// writes scale/shift). Removes the 5 reduce_kernel launches.
__global__ __launch_bounds__(256, 1) void mlp_kernel(
    const _Float16* __restrict__ A, const _Float16* __restrict__ w1t,
    const _Float16* __restrict__ w2t,
    const float* __restrict__ b1, const float* __restrict__ b2,
    _Float16* __restrict__ hpre, float* __restrict__ psum, float* __restrict__ psq,
    const float* __restrict__ gamma, const float* __restrict__ beta,
    float* __restrict__ ssout, int* __restrict__ dctr,
    int M)
{
    __shared__ _Float16 hid[2][8 * 4 * 64 * 8];   // 2 x 32 KB, fragment-major
    int tid = threadIdx.x;
    int w = tid >> 6, lane = tid & 63;
    int ln = lane & 15, quad = lane >> 4;
    const f32x4 zero = {0.f, 0.f, 0.f, 0.f};

    int t0 = (blockIdx.x * TILES) >> 8;        // contiguous tile range
    int t1 = ((blockIdx.x + 1) * TILES) >> 8;

    // ---- prologue tile-t0 activation loads (deepest latency, issue first) --
    f16x8 ba[4][4];   // [ns][kt], 64 VGPR
    #pragma unroll
    for (int ns = 0; ns < 4; ++ns) {
        int row = t0 * 64 + ns * 16 + ln;
        row = row < M ? row : M - 1;
        #pragma unroll
        for (int kt = 0; kt < 4; ++kt)
            ba[ns][kt] = *(const f16x8*)(A + (size_t)row * 128 + kt * 32 + quad * 8);
    }

    // ---- W1 fragments: wave's 64 hidden cols x 128 k (64 VGPR, whole kernel)
    f16x8 w1f[4][4];
    #pragma unroll
    for (int n1 = 0; n1 < 4; ++n1)
        #pragma unroll
        for (int kt = 0; kt < 4; ++kt)
            w1f[n1][kt] = *(const f16x8*)(w1t + (w * 64 + n1 * 16 + ln) * 128 + kt * 32 + quad * 8);
    f32x4 b1v[4];
    #pragma unroll
    for (int n1 = 0; n1 < 4; ++n1)
        b1v[n1] = *(const f32x4*)(b1 + w * 64 + n1 * 16 + quad * 4);

    // ---- W2 fragments: wave's 32 out cols x 256 k (64 VGPR, whole kernel) --
    f16x8 w2f[2][8];
    #pragma unroll
    for (int n2 = 0; n2 < 2; ++n2)
        #pragma unroll
        for (int kt2 = 0; kt2 < 8; ++kt2)
            w2f[n2][kt2] = *(const f16x8*)(w2t + (w * 32 + n2 * 16 + ln) * 256 + kt2 * 32 + quad * 8);
    f32x4 b2v[2];
    #pragma unroll
    for (int n2 = 0; n2 < 2; ++n2)
        b2v[n2] = *(const f32x4*)(b2 + w * 32 + n2 * 16 + quad * 4);

    f32x4 ssum[2] = {zero, zero};
    f32x4 sqsum[2] = {zero, zero};

    for (int t = t0; t < t1; ++t) {
        int node0 = t * 64;
        _Float16* hb = hid[t & 1];

        // GEMM1: consume ba[ns]; refill ba[ns] with tile t+1 rows after use
        #pragma unroll
        for (int ns = 0; ns < 4; ++ns) {
            f32x4 acc1[4] = {zero, zero, zero, zero};
            #pragma unroll
            for (int kt = 0; kt < 4; ++kt)
                #pragma unroll
                for (int n1 = 0; n1 < 4; ++n1)
                    acc1[n1] = __builtin_amdgcn_mfma_f32_16x16x32_f16(w1f[n1][kt], ba[ns][kt], acc1[n1], 0, 0, 0);
            {   // refill (clamped; unused garbage on last iteration is harmless)
                int row = (t + 1) * 64 + ns * 16 + ln;
                row = row < M ? row : M - 1;
                #pragma unroll
                for (int kt = 0; kt < 4; ++kt)
                    ba[ns][kt] = *(const f16x8*)(A + (size_t)row * 128 + kt * 32 + quad * 8);
            }
            #pragma unroll
            for (int n1 = 0; n1 < 4; ++n1) {
                int a = w * 4 + n1;               // 16-col tile of hidden dim
                f16x4 pk;
                #pragma unroll
                for (int r = 0; r < 4; ++r) {
                    float v = acc1[n1][r] + b1v[n1][r];
                    v = v > 0.f ? v : 0.f;
                    pk[r] = (_Float16)v;
                }
                int lp = ((a & 1) * 2 + (quad >> 1)) * 16 + ln;      // reader's lane id
                int off = (((a >> 1) * 4 + ns) * 64 + lp) * 8 + (quad & 1) * 4;  // f16 units
                *(f16x4*)(hb + off) = pk;
            }
        }

        __syncthreads();

        // GEMM2: wave's 32 out cols x 64 nodes from frag-major hid
        #pragma unroll
        for (int ns = 0; ns < 4; ++ns) {
            f32x4 acc2[2] = {zero, zero};
            #pragma unroll
            for (int kt2 = 0; kt2 < 8; ++kt2) {
                f16x8 bf = *(const f16x8*)(hb + ((kt2 * 4 + ns) * 64 + lane) * 8);
                acc2[0] = __builtin_amdgcn_mfma_f32_16x16x32_f16(w2f[0][kt2], bf, acc2[0], 0, 0, 0);
                acc2[1] = __builtin_amdgcn_mfma_f32_16x16x32_f16(w2f[1][kt2], bf, acc2[1], 0, 0, 0);
            }
            int node = node0 + ns * 16 + ln;
            bool valid = node < M;
            #pragma unroll
            for (int n2 = 0; n2 < 2; ++n2) {
                f32x4 v;
                f16x4 pk;
                #pragma unroll
                for (int r = 0; r < 4; ++r) {
                    v[r] = acc2[n2][r] + b2v[n2][r];
                    pk[r] = (_Float16)v[r];
                }
                if (valid) {
                    *(f16x4*)(hpre + (size_t)node * 128 + w * 32 + n2 * 16 + quad * 4) = pk;
                    ssum[n2] += v;
                    sqsum[n2] += v * v;
                }
            }
        }
        // no trailing barrier: next tile writes the OTHER hid buffer
    }

    // reduce stats over the 16 node-lanes; wave owns its 32 cols exclusively
    #pragma unroll
    for (int n2 = 0; n2 < 2; ++n2)
        #pragma unroll
        for (int off = 1; off < 16; off <<= 1)
            #pragma unroll
            for (int r = 0; r < 4; ++r) {
                ssum[n2][r] += __shfl_xor(ssum[n2][r], off, 64);
                sqsum[n2][r] += __shfl_xor(sqsum[n2][r], off, 64);
            }
    if (ln == 0) {
        #pragma unroll
        for (int n2 = 0; n2 < 2; ++n2) {
            *(f32x4*)(psum + blockIdx.x * 128 + w * 32 + n2 * 16 + quad * 4) = ssum[n2];
            *(f32x4*)(psq + blockIdx.x * 128 + w * 32 + n2 * 16 + quad * 4) = sqsum[n2];
        }
    }

    // ---- last-block BN reduction: psum/psq[256][128] -> ss[256] ----
    __threadfence();                       // release partials device-wide
    __shared__ int amlast;
    if (tid == 0) amlast = (atomicAdd(dctr, 1) == PBLK - 1) ? 1 : 0;
    __syncthreads();
    if (amlast) {
        __threadfence();                   // acquire all partials
        int c = tid & 127, half = tid >> 7;
        float s = 0.f, qq = 0.f;
        for (int b = half * 128; b < half * 128 + 128; ++b) {
            s += psum[b * 128 + c];
            qq += psq[b * 128 + c];
        }
        __shared__ float rs2[128], rq2[128];
        if (half == 1) { rs2[c] = s; rq2[c] = qq; }
        __syncthreads();
        if (half == 0) {
            s += rs2[c]; qq += rq2[c];
            const float invN = 1.0f / NN;
            float mean = s * invN;
            float var = qq * invN - mean * mean;
            float inv = rsqrtf(var + 1e-5f);
            float scale = gamma[c] * inv;
            ssout[c] = scale;
            ssout[128 + c] = beta[c] - mean * scale;
        }
    }
}

// ---------------- final BN apply (no relu) -> fp32 d_out ----------------
__global__ __launch_bounds__(256) void final_bn_kernel(
    const _Float16* __restrict__ hpre, float* __restrict__ out,
    const float* __restrict__ ss)
{
    int idx = blockIdx.x * 256 + threadIdx.x;   // NN*16
    int q = idx & 15;
    f16x8 x = ((const f16x8*)hpre)[idx];
    f32x4 sc0 = ((const f32x4*)ss)[2 * q],        sc1 = ((const f32x4*)ss)[2 * q + 1];
    f32x4 sh0 = ((const f32x4*)(ss + 128))[2 * q], sh1 = ((const f32x4*)(ss + 128))[2 * q + 1];
    f32x4 y0, y1;
    #pragma unroll
    for (int j = 0; j < 4; ++j) {
        y0[j] = (float)x[j] * sc0[j] + sh0[j];
        y1[j] = (float)x[j + 4] * sc1[j] + sh1[j];
    }
    ((f32x4*)out)[2 * idx] = y0;
    ((f32x4*)out)[2 * idx + 1] = y1;
}

extern "C" void kernel_launch(void* const* d_in, const int* in_sizes, int n_in,
                              void* d_out, int out_size, void* d_ws, size_t ws_size,
                              hipStream_t stream)
{
    const int* an  = (const int*)d_in[0];
    const int* fc  = (const int*)d_in[1];
    const int* ct  = (const int*)d_in[2];
    const int* hy  = (const int*)d_in[3];
    const int* nh  = (const int*)d_in[4];
    const int* ar  = (const int*)d_in[5];
    const int* ei  = (const int*)d_in[6];
    const int* econ = (const int*)d_in[7];
    const int* earo = (const int*)d_in[8];
    const int* ebt  = (const int*)d_in[9];
    const int* ebd  = (const int*)d_in[10];
    const int* ebs  = (const int*)d_in[11];
    const float* ean = (const float*)d_in[12];
    const float* efc = (const float*)d_in[13];
    const float* ect = (const float*)d_in[14];
    const float* ehy = (const float*)d_in[15];
    const float* enh = (const float*)d_in[16];
    const float* ear = (const float*)d_in[17];
    const float* e_conj   = (const float*)d_in[18];
    const float* e_arom   = (const float*)d_in[19];
    const float* e_btype  = (const float*)d_in[20];
    const float* e_bdir   = (const float*)d_in[21];
    const float* e_bstereo= (const float*)d_in[22];
    const float* mlp_w1 = (const float*)d_in[23];
    const float* mlp_b1 = (const float*)d_in[24];
    const float* mlp_w2 = (const float*)d_in[25];
    const float* mlp_b2 = (const float*)d_in[26];
    const float* bn_gamma = (const float*)d_in[27];
    const float* bn_beta  = (const float*)d_in[28];

    // workspace carve (base 256B-aligned; all segments stay 16B-aligned)
    _Float16* h0   = (_Float16*)d_ws;                   // N*128 fp16
    _Float16* agg  = h0 + (size_t)NN * DD;              // N*128 fp16
    _Float16* hpre = agg + (size_t)NN * DD;             // N*128 fp16
    _Float16* w1t  = hpre + (size_t)NN * DD;            // 5*256*128 fp16
    _Float16* w2t  = w1t + LL * 256 * 128;              // 5*128*256 fp16
    _Float16* ctab5= w2t + LL * 128 * 256;              // 5*CTROWS*128 fp16
    float*    psum = (float*)(ctab5 + (size_t)LL * CTROWS * DD);  // MBLK*128
    float*    psq  = psum + MBLK * 128;                 // MBLK*128
    float*    ss   = psq + MBLK * 128;                  // 256 (scale|shift)
    float*    idss = ss + 256;                          // 256 identity
    int* rowstart = (int*)(idss + 256);                 // NN+1
    int* cursor   = rowstart + NN + 8;                  // NN
    int* rec      = cursor + NN;                        // EE
    int* btot     = rec + EE;                           // SBLK
    int* boff     = btot + SBLK + 8;                    // SBLK
    int* dcnt     = boff + SBLK + 8;                    // 8 per-layer counters

    convw_kernel<<<1281, 256, 0, stream>>>(mlp_w1, mlp_w2, w1t, w2t, idss, dcnt);
    seed_kernel<<<6250, 256, 0, stream>>>(an, fc, ct, hy, nh, ar,
                                          ean, efc, ect, ehy, enh, ear, h0);
    ctab_kernel<<<1610, 256, 0, stream>>>(e_conj, e_arom, e_btype,
                                          e_bdir, e_bstereo, ctab5);

    // CSR build (re-run every call: ws is re-poisoned)
    hipMemsetAsync(cursor, 0, NN * sizeof(int), stream);
    count_kernel<<<2344, 256, 0, stream>>>(ei, cursor);
    btot_kernel<<<SBLK, 1024, 0, stream>>>(cursor, btot);
    bscan_kernel<<<1, 128, 0, stream>>>(btot, boff, rowstart);
    apply_kernel<<<SBLK, 1024, 0, stream>>>(cursor, boff, rowstart, cursor);
    fill_kernel<<<2344, 256, 0, stream>>>(ei, cursor, rec,
                                          econ, earo, ebt, ebd, ebs);

    for (int l = 0; l < LL; ++l) {
        gather_bn_kernel<<<6250, 256, 0, stream>>>(
            (l == 0) ? h0 : hpre, agg, rowstart, rec,
            ctab5 + (size_t)l * CTROWS * DD,
            (l == 0) ? idss : ss, (l == 0) ? 0 : 1);
        mlp_kernel<<<PBLK, 256, 0, stream>>>(
            agg, w1t + l * 32768, w2t + l * 32768,
            mlp_b1 + l * 256, mlp_b2 + l * 128,
            hpre, psum, psq,
            bn_gamma + l * 128, bn_beta + l * 128,
            ss, dcnt + l, NN);
    }
    final_bn_kernel<<<6250, 256, 0, stream>>>(hpre, (float*)d_out, ss);
}

// Round 13
// 564.649 us; speedup vs baseline: 1.4828x; 1.4828x over previous
//
#include <hip/hip_runtime.h>

#define NN 100000
#define EE 600000
#define DD 128
#define LL 5
#define CTROWS 5152   // 2*2*23*8*7 combined edge-feature rows
#define MBLK 1563     // psum/psq allocation rows
#define TILES 1563    // ceil(NN/64) 64-node tiles for persistent mlp
#define PBLK 256      // persistent mlp blocks (1 per CU)
#define SBLK 98       // scan blocks: 98*1024 >= NN

typedef float f32x4 __attribute__((ext_vector_type(4)));
typedef _Float16 f16x8 __attribute__((ext_vector_type(8)));
typedef _Float16 f16x4 __attribute__((ext_vector_type(4)));

// ---------------- seed: h = sum of 6 atom-feature embeddings (fp16 out) ------
__global__ __launch_bounds__(256) void seed_kernel(
    const int* __restrict__ an, const int* __restrict__ fc,
    const int* __restrict__ ct, const int* __restrict__ hy,
    const int* __restrict__ nh, const int* __restrict__ ar,
    const float* __restrict__ ean, const float* __restrict__ efc,
    const float* __restrict__ ect, const float* __restrict__ ehy,
    const float* __restrict__ enh, const float* __restrict__ ear,
    _Float16* __restrict__ h)
{
    int idx = blockIdx.x * 256 + threadIdx.x;   // NN*16 exactly
    int n = idx >> 4, q = idx & 15;
    f32x4 a0 = ((const f32x4*)(ean + an[n] * DD))[2 * q];
    f32x4 a1 = ((const f32x4*)(ean + an[n] * DD))[2 * q + 1];
    a0 += ((const f32x4*)(efc + fc[n] * DD))[2 * q];
    a1 += ((const f32x4*)(efc + fc[n] * DD))[2 * q + 1];
    a0 += ((const f32x4*)(ect + ct[n] * DD))[2 * q];
    a1 += ((const f32x4*)(ect + ct[n] * DD))[2 * q + 1];
    a0 += ((const f32x4*)(ehy + hy[n] * DD))[2 * q];
    a1 += ((const f32x4*)(ehy + hy[n] * DD))[2 * q + 1];
    a0 += ((const f32x4*)(enh + nh[n] * DD))[2 * q];
    a1 += ((const f32x4*)(enh + nh[n] * DD))[2 * q + 1];
    a0 += ((const f32x4*)(ear + ar[n] * DD))[2 * q];
    a1 += ((const f32x4*)(ear + ar[n] * DD))[2 * q + 1];
    f16x8 o;
    #pragma unroll
    for (int j = 0; j < 4; ++j) { o[j] = (_Float16)a0[j]; o[j + 4] = (_Float16)a1[j]; }
    ((f16x8*)h)[idx] = o;
}

// -------- weight convert+transpose to fp16 [n][k] + idss, one launch --------
__global__ __launch_bounds__(256) void convw_kernel(
    const float* __restrict__ w1, const float* __restrict__ w2,
    _Float16* __restrict__ w1t, _Float16* __restrict__ w2t,
    float* __restrict__ idss)
{
    int b = blockIdx.x;
    if (b < 640) {
        int idx = b * 256 + threadIdx.x;        // 5*256*128
        int l = idx >> 15, rem = idx & 32767;
        int n = rem >> 7, k = rem & 127;
        w1t[idx] = (_Float16)w1[l * 32768 + k * 256 + n];
    } else if (b < 1280) {
        int idx = (b - 640) * 256 + threadIdx.x; // 5*128*256
        int l = idx >> 15, rem = idx & 32767;
        int n = rem >> 8, k = rem & 255;
        w2t[idx] = (_Float16)w2[l * 32768 + k * 128 + n];
    } else {
        int t = threadIdx.x;
        idss[t] = (t < 128) ? 1.0f : 0.0f;
    }
}

// ---------------- CSR build: count, 3-phase scan, fill ----------------
__global__ __launch_bounds__(256) void count_kernel(const int* __restrict__ ei,
                                                    int* __restrict__ cursor)
{
    int e = blockIdx.x * 256 + threadIdx.x;
    if (e < EE) atomicAdd(&cursor[ei[EE + e]], 1);
}

__global__ __launch_bounds__(1024) void btot_kernel(const int* __restrict__ cursor,
                                                    int* __restrict__ btot)
{
    __shared__ int wsum[16];
    int tid = threadIdx.x;
    int i = blockIdx.x * 1024 + tid;
    int x = (i < NN) ? cursor[i] : 0;
    #pragma unroll
    for (int off = 1; off < 64; off <<= 1) x += __shfl_xor(x, off, 64);
    if ((tid & 63) == 0) wsum[tid >> 6] = x;
    __syncthreads();
    if (tid == 0) {
        int s = 0;
        #pragma unroll
        for (int w = 0; w < 16; ++w) s += wsum[w];
        btot[blockIdx.x] = s;
    }
}

__global__ __launch_bounds__(128) void bscan_kernel(const int* __restrict__ btot,
                                                    int* __restrict__ boff,
                                                    int* __restrict__ rowstart)
{
    __shared__ int w0;
    int t = threadIdx.x;
    int lane = t & 63, wv = t >> 6;
    int x = (t < SBLK) ? btot[t] : 0;
    int incl = x;
    #pragma unroll
    for (int off = 1; off < 64; off <<= 1) {
        int u = __shfl_up(incl, off, 64);
        if (lane >= off) incl += u;
    }
    if (wv == 0 && lane == 63) w0 = incl;
    __syncthreads();
    if (wv == 1) incl += w0;
    if (t < SBLK) boff[t] = incl - x;
    if (t == 127) rowstart[NN] = incl;   // grand total
}

__global__ __launch_bounds__(1024) void apply_kernel(const int* __restrict__ cursorin,
                                                     const int* __restrict__ boff,
                                                     int* __restrict__ rowstart,
                                                     int* __restrict__ cursor)
{
    __shared__ int wsum[16];
    int tid = threadIdx.x;
    int lane = tid & 63, wv = tid >> 6;
    int i = blockIdx.x * 1024 + tid;
    int x = (i < NN) ? cursorin[i] : 0;
    int incl = x;
    #pragma unroll
    for (int off = 1; off < 64; off <<= 1) {
        int u = __shfl_up(incl, off, 64);
        if (lane >= off) incl += u;
    }
    if (lane == 63) wsum[wv] = incl;
    __syncthreads();
    int pre = 0;
    #pragma unroll
    for (int w = 0; w < 16; ++w) pre += (w < wv) ? wsum[w] : 0;
    int excl = boff[blockIdx.x] + pre + incl - x;
    if (i < NN) { rowstart[i] = excl; cursor[i] = excl; }
}

__global__ __launch_bounds__(256) void fill_kernel(
    const int* __restrict__ ei, int* __restrict__ cursor, int* __restrict__ rec,
    const int* __restrict__ f0, const int* __restrict__ f1,
    const int* __restrict__ f2, const int* __restrict__ f3,
    const int* __restrict__ f4)
{
    int e = blockIdx.x * 256 + threadIdx.x;
    if (e >= EE) return;
    int dst = ei[EE + e];
    int p = atomicAdd(&cursor[dst], 1);
    int f = f0[e] + 2 * (f1[e] + 2 * (f2[e] + 23 * (f3[e] + 8 * f4[e])));
    rec[p] = ei[e] | (f << 17);
}

// ------------- combined edge-embedding tables, ALL 5 layers (fp16 out) -------
__global__ __launch_bounds__(256) void ctab_kernel(
    const float* __restrict__ ec, const float* __restrict__ ea,
    const float* __restrict__ eb, const float* __restrict__ ed,
    const float* __restrict__ es, _Float16* __restrict__ ctab5)
{
    int idx = blockIdx.x * 256 + threadIdx.x;   // 5*CTROWS*16 exactly (1610 blocks)
    int q = idx & 15;
    int grow = idx >> 4;                        // 0 .. 5*CTROWS
    int l = grow / CTROWS, row = grow - l * CTROWS;
    int conj = row & 1, arom = (row >> 1) & 1;
    int r2 = row >> 2;
    int bt = r2 % 23, r3 = r2 / 23;
    int bd = r3 & 7, bs = r3 >> 3;
    const float* ecl = ec + l * 3 * DD;
    const float* eal = ea + l * 3 * DD;
    const float* ebl = eb + l * 23 * DD;
    const float* edl = ed + l * 8 * DD;
    const float* esl = es + l * 7 * DD;
    f32x4 a0 = ((const f32x4*)(ecl + conj * DD))[2 * q]
             + ((const f32x4*)(eal + arom * DD))[2 * q]
             + ((const f32x4*)(ebl + bt * DD))[2 * q]
             + ((const f32x4*)(edl + bd * DD))[2 * q]
             + ((const f32x4*)(esl + bs * DD))[2 * q];
    f32x4 a1 = ((const f32x4*)(ecl + conj * DD))[2 * q + 1]
             + ((const f32x4*)(eal + arom * DD))[2 * q + 1]
             + ((const f32x4*)(ebl + bt * DD))[2 * q + 1]
             + ((const f32x4*)(edl + bd * DD))[2 * q + 1]
             + ((const f32x4*)(esl + bs * DD))[2 * q + 1];
    f16x8 o;
    #pragma unroll
    for (int j = 0; j < 4; ++j) { o[j] = (_Float16)a0[j]; o[j + 4] = (_Float16)a1[j]; }
    ((f16x8*)ctab5)[idx] = o;
}

// ---------------- gather-aggregate with fused BN(+relu), fp16 in/out ---------
// Round-8-VERIFIED: single chain, 6250 blocks, 3-deep pipeline, packed-fp16
// BN math + f32 widening accumulate. (r11 dual-chain and r10 fusion both
// regressed and were reverted.)
__global__ __launch_bounds__(256) void gather_bn_kernel(
    const _Float16* __restrict__ hsrc, _Float16* __restrict__ agg,
    const int* __restrict__ rowstart, const int* __restrict__ rec,
    const _Float16* __restrict__ ctab, const float* __restrict__ ss, int dorelu)
{
    int idx = blockIdx.x * 256 + threadIdx.x;   // NN*16
    int n = idx >> 4, q = idx & 15;
    f16x8 sc8, sh8, clampv;
    _Float16 cl = dorelu ? (_Float16)0.0f : (_Float16)(-60000.0f);
    #pragma unroll
    for (int j = 0; j < 8; ++j) {
        sc8[j] = (_Float16)ss[q * 8 + j];
        sh8[j] = (_Float16)ss[128 + q * 8 + j];
        clampv[j] = cl;
    }
    int p0 = rowstart[n], p1 = rowstart[n + 1];
    f16x8 x = ((const f16x8*)hsrc)[idx];
    f16x8 c0 = ((const f16x8*)ctab)[q];           // self_vec == ctab row 0
    f16x8 ts = __builtin_elementwise_max((f16x8)(x * sc8 + sh8), clampv);
    float v[8];
    #pragma unroll
    for (int j = 0; j < 8; ++j) v[j] = (float)ts[j] + (float)c0[j];

    if (p0 < p1) {
        // prologue: 2 staged rows + rec 3 ahead
        int r0 = rec[p0];
        int r1 = (p0 + 1 < p1) ? rec[p0 + 1] : r0;
        int rr2 = (p0 + 2 < p1) ? rec[p0 + 2] : r1;
        f16x8 y0 = *(const f16x8*)(hsrc + (size_t)(r0 & 0x1FFFF) * DD + q * 8);
        f16x8 e0 = *(const f16x8*)(ctab + (size_t)(((unsigned)r0) >> 17) * DD + q * 8);
        f16x8 y1 = *(const f16x8*)(hsrc + (size_t)(r1 & 0x1FFFF) * DD + q * 8);
        f16x8 e1 = *(const f16x8*)(ctab + (size_t)(((unsigned)r1) >> 17) * DD + q * 8);
        for (int p = p0; p < p1; ++p) {
            int r3 = (p + 3 < p1) ? rec[p + 3] : rr2;
            f16x8 y2 = *(const f16x8*)(hsrc + (size_t)(rr2 & 0x1FFFF) * DD + q * 8);
            f16x8 e2 = *(const f16x8*)(ctab + (size_t)(((unsigned)rr2) >> 17) * DD + q * 8);
            f16x8 t = __builtin_elementwise_max((f16x8)(y0 * sc8 + sh8), clampv);
            f16x8 u = t + e0;
            #pragma unroll
            for (int j = 0; j < 8; ++j) v[j] += (float)u[j];
            y0 = y1; e0 = e1; y1 = y2; e1 = e2; rr2 = r3;
        }
    }
    f16x8 o;
    #pragma unroll
    for (int j = 0; j < 8; ++j) o[j] = (_Float16)v[j];
    ((f16x8*)agg)[idx] = o;
}

// ---------------- fused MLP: hpre = relu(agg@W1+b1)@W2+b2 + column partials --
// Round-8-verified persistent structure: grid=256 (1 block/CU), both weight
// sets in registers (512-VGPR budget at 1 wave/SIMD), double-buffered hid,
// one barrier per tile, ba refill right after last use. (r12's in-kernel
// last-block BN reduction regressed badly -- serial cross-XCD tail on one
// CU -- reverted to the separate 128-block reduce_kernel.)
__global__ __launch_bounds__(256, 1) void mlp_kernel(
    const _Float16* __restrict__ A, const _Float16* __restrict__ w1t,
    const _Float16* __restrict__ w2t,
    const float* __restrict__ b1, const float* __restrict__ b2,
    _Float16* __restrict__ hpre, float* __restrict__ psum, float* __restrict__ psq,
    int M)
{
    __shared__ _Float16 hid[2][8 * 4 * 64 * 8];   // 2 x 32 KB, fragment-major
    int tid = threadIdx.x;
    int w = tid >> 6, lane = tid & 63;
    int ln = lane & 15, quad = lane >> 4;
    const f32x4 zero = {0.f, 0.f, 0.f, 0.f};

    int t0 = (blockIdx.x * TILES) >> 8;        // contiguous tile range
    int t1 = ((blockIdx.x + 1) * TILES) >> 8;

    // ---- prologue tile-t0 activation loads (deepest latency, issue first) --
    f16x8 ba[4][4];   // [ns][kt], 64 VGPR
    #pragma unroll
    for (int ns = 0; ns < 4; ++ns) {
        int row = t0 * 64 + ns * 16 + ln;
        row = row < M ? row : M - 1;
        #pragma unroll
        for (int kt = 0; kt < 4; ++kt)
            ba[ns][kt] = *(const f16x8*)(A + (size_t)row * 128 + kt * 32 + quad * 8);
    }

    // ---- W1 fragments: wave's 64 hidden cols x 128 k (64 VGPR, whole kernel)
    f16x8 w1f[4][4];
    #pragma unroll
    for (int n1 = 0; n1 < 4; ++n1)
        #pragma unroll
        for (int kt = 0; kt < 4; ++kt)
            w1f[n1][kt] = *(const f16x8*)(w1t + (w * 64 + n1 * 16 + ln) * 128 + kt * 32 + quad * 8);
    f32x4 b1v[4];
    #pragma unroll
    for (int n1 = 0; n1 < 4; ++n1)
        b1v[n1] = *(const f32x4*)(b1 + w * 64 + n1 * 16 + quad * 4);

    // ---- W2 fragments: wave's 32 out cols x 256 k (64 VGPR, whole kernel) --
    f16x8 w2f[2][8];
    #pragma unroll
    for (int n2 = 0; n2 < 2; ++n2)
        #pragma unroll
        for (int kt2 = 0; kt2 < 8; ++kt2)
            w2f[n2][kt2] = *(const f16x8*)(w2t + (w * 32 + n2 * 16 + ln) * 256 + kt2 * 32 + quad * 8);
    f32x4 b2v[2];
    #pragma unroll
    for (int n2 = 0; n2 < 2; ++n2)
        b2v[n2] = *(const f32x4*)(b2 + w * 32 + n2 * 16 + quad * 4);

    f32x4 ssum[2] = {zero, zero};
    f32x4 sqsum[2] = {zero, zero};

    for (int t = t0; t < t1; ++t) {
        int node0 = t * 64;
        _Float16* hb = hid[t & 1];

        // GEMM1: consume ba[ns]; refill ba[ns] with tile t+1 rows after use
        #pragma unroll
        for (int ns = 0; ns < 4; ++ns) {
            f32x4 acc1[4] = {zero, zero, zero, zero};
            #pragma unroll
            for (int kt = 0; kt < 4; ++kt)
                #pragma unroll
                for (int n1 = 0; n1 < 4; ++n1)
                    acc1[n1] = __builtin_amdgcn_mfma_f32_16x16x32_f16(w1f[n1][kt], ba[ns][kt], acc1[n1], 0, 0, 0);
            {   // refill (clamped; unused garbage on last iteration is harmless)
                int row = (t + 1) * 64 + ns * 16 + ln;
                row = row < M ? row : M - 1;
                #pragma unroll
                for (int kt = 0; kt < 4; ++kt)
                    ba[ns][kt] = *(const f16x8*)(A + (size_t)row * 128 + kt * 32 + quad * 8);
            }
            #pragma unroll
            for (int n1 = 0; n1 < 4; ++n1) {
                int a = w * 4 + n1;               // 16-col tile of hidden dim
                f16x4 pk;
                #pragma unroll
                for (int r = 0; r < 4; ++r) {
                    float v = acc1[n1][r] + b1v[n1][r];
                    v = v > 0.f ? v : 0.f;
                    pk[r] = (_Float16)v;
                }
                int lp = ((a & 1) * 2 + (quad >> 1)) * 16 + ln;      // reader's lane id
                int off = (((a >> 1) * 4 + ns) * 64 + lp) * 8 + (quad & 1) * 4;  // f16 units
                *(f16x4*)(hb + off) = pk;
            }
        }

        __syncthreads();

        // GEMM2: wave's 32 out cols x 64 nodes from frag-major hid
        #pragma unroll
        for (int ns = 0; ns < 4; ++ns) {
            f32x4 acc2[2] = {zero, zero};
            #pragma unroll
            for (int kt2 = 0; kt2 < 8; ++kt2) {
                f16x8 bf = *(const f16x8*)(hb + ((kt2 * 4 + ns) * 64 + lane) * 8);
                acc2[0] = __builtin_amdgcn_mfma_f32_16x16x32_f16(w2f[0][kt2], bf, acc2[0], 0, 0, 0);
                acc2[1] = __builtin_amdgcn_mfma_f32_16x16x32_f16(w2f[1][kt2], bf, acc2[1], 0, 0, 0);
            }
            int node = node0 + ns * 16 + ln;
            bool valid = node < M;
            #pragma unroll
            for (int n2 = 0; n2 < 2; ++n2) {
                f32x4 v;
                f16x4 pk;
                #pragma unroll
                for (int r = 0; r < 4; ++r) {
                    v[r] = acc2[n2][r] + b2v[n2][r];
                    pk[r] = (_Float16)v[r];
                }
                if (valid) {
                    *(f16x4*)(hpre + (size_t)node * 128 + w * 32 + n2 * 16 + quad * 4) = pk;
                    ssum[n2] += v;
                    sqsum[n2] += v * v;
                }
            }
        }
        // no trailing barrier: next tile writes the OTHER hid buffer
    }

    // reduce stats over the 16 node-lanes; wave owns its 32 cols exclusively
    #pragma unroll
    for (int n2 = 0; n2 < 2; ++n2)
        #pragma unroll
        for (int off = 1; off < 16; off <<= 1)
            #pragma unroll
            for (int r = 0; r < 4; ++r) {
                ssum[n2][r] += __shfl_xor(ssum[n2][r], off, 64);
                sqsum[n2][r] += __shfl_xor(sqsum[n2][r], off, 64);
            }
    if (ln == 0) {
        #pragma unroll
        for (int n2 = 0; n2 < 2; ++n2) {
            *(f32x4*)(psum + blockIdx.x * 128 + w * 32 + n2 * 16 + quad * 4) = ssum[n2];
            *(f32x4*)(psq + blockIdx.x * 128 + w * 32 + n2 * 16 + quad * 4) = sqsum[n2];
        }
    }
}

// ---------------- fold partials -> scale/shift for BN ----------------
__global__ __launch_bounds__(256) void reduce_kernel(
    const float* __restrict__ psum, const float* __restrict__ psq,
    const float* __restrict__ gamma, const float* __restrict__ beta,
    float* __restrict__ ss, int nblk)
{
    int c = blockIdx.x;                  // 0..127
    int tid = threadIdx.x;
    float s = 0.f, q = 0.f;
    for (int b = tid; b < nblk; b += 256) {
        s += psum[b * 128 + c];
        q += psq[b * 128 + c];
    }
    #pragma unroll
    for (int off = 1; off < 64; off <<= 1) {
        s += __shfl_xor(s, off, 64);
        q += __shfl_xor(q, off, 64);
    }
    __shared__ float rs[4], rq[4];
    int wave = tid >> 6;
    if ((tid & 63) == 0) { rs[wave] = s; rq[wave] = q; }
    __syncthreads();
    if (tid == 0) {
        s = rs[0] + rs[1] + rs[2] + rs[3];
        q = rq[0] + rq[1] + rq[2] + rq[3];
        const float invN = 1.0f / NN;
        float mean = s * invN;
        float var = q * invN - mean * mean;
        float inv = rsqrtf(var + 1e-5f);
        float scale = gamma[c] * inv;
        ss[c] = scale;
        ss[128 + c] = beta[c] - mean * scale;
    }
}

// ---------------- final BN apply (no relu) -> fp32 d_out ----------------
__global__ __launch_bounds__(256) void final_bn_kernel(
    const _Float16* __restrict__ hpre, float* __restrict__ out,
    const float* __restrict__ ss)
{
    int idx = blockIdx.x * 256 + threadIdx.x;   // NN*16
    int q = idx & 15;
    f16x8 x = ((const f16x8*)hpre)[idx];
    f32x4 sc0 = ((const f32x4*)ss)[2 * q],        sc1 = ((const f32x4*)ss)[2 * q + 1];
    f32x4 sh0 = ((const f32x4*)(ss + 128))[2 * q], sh1 = ((const f32x4*)(ss + 128))[2 * q + 1];
    f32x4 y0, y1;
    #pragma unroll
    for (int j = 0; j < 4; ++j) {
        y0[j] = (float)x[j] * sc0[j] + sh0[j];
        y1[j] = (float)x[j + 4] * sc1[j] + sh1[j];
    }
    ((f32x4*)out)[2 * idx] = y0;
    ((f32x4*)out)[2 * idx + 1] = y1;
}

extern "C" void kernel_launch(void* const* d_in, const int* in_sizes, int n_in,
                              void* d_out, int out_size, void* d_ws, size_t ws_size,
                              hipStream_t stream)
{
    const int* an  = (const int*)d_in[0];
    const int* fc  = (const int*)d_in[1];
    const int* ct  = (const int*)d_in[2];
    const int* hy  = (const int*)d_in[3];
    const int* nh  = (const int*)d_in[4];
    const int* ar  = (const int*)d_in[5];
    const int* ei  = (const int*)d_in[6];
    const int* econ = (const int*)d_in[7];
    const int* earo = (const int*)d_in[8];
    const int* ebt  = (const int*)d_in[9];
    const int* ebd  = (const int*)d_in[10];
    const int* ebs  = (const int*)d_in[11];
    const float* ean = (const float*)d_in[12];
    const float* efc = (const float*)d_in[13];
    const float* ect = (const float*)d_in[14];
    const float* ehy = (const float*)d_in[15];
    const float* enh = (const float*)d_in[16];
    const float* ear = (const float*)d_in[17];
    const float* e_conj   = (const float*)d_in[18];
    const float* e_arom   = (const float*)d_in[19];
    const float* e_btype  = (const float*)d_in[20];
    const float* e_bdir   = (const float*)d_in[21];
    const float* e_bstereo= (const float*)d_in[22];
    const float* mlp_w1 = (const float*)d_in[23];
    const float* mlp_b1 = (const float*)d_in[24];
    const float* mlp_w2 = (const float*)d_in[25];
    const float* mlp_b2 = (const float*)d_in[26];
    const float* bn_gamma = (const float*)d_in[27];
    const float* bn_beta  = (const float*)d_in[28];

    // workspace carve (base 256B-aligned; all segments stay 16B-aligned)
    _Float16* h0   = (_Float16*)d_ws;                   // N*128 fp16
    _Float16* agg  = h0 + (size_t)NN * DD;              // N*128 fp16
    _Float16* hpre = agg + (size_t)NN * DD;             // N*128 fp16
    _Float16* w1t  = hpre + (size_t)NN * DD;            // 5*256*128 fp16
    _Float16* w2t  = w1t + LL * 256 * 128;              // 5*128*256 fp16
    _Float16* ctab5= w2t + LL * 128 * 256;              // 5*CTROWS*128 fp16
    float*    psum = (float*)(ctab5 + (size_t)LL * CTROWS * DD);  // MBLK*128
    float*    psq  = psum + MBLK * 128;                 // MBLK*128
    float*    ss   = psq + MBLK * 128;                  // 256 (scale|shift)
    float*    idss = ss + 256;                          // 256 identity
    int* rowstart = (int*)(idss + 256);                 // NN+1
    int* cursor   = rowstart + NN + 8;                  // NN
    int* rec      = cursor + NN;                        // EE
    int* btot     = rec + EE;                           // SBLK
    int* boff     = btot + SBLK + 8;                    // SBLK

    convw_kernel<<<1281, 256, 0, stream>>>(mlp_w1, mlp_w2, w1t, w2t, idss);
    seed_kernel<<<6250, 256, 0, stream>>>(an, fc, ct, hy, nh, ar,
                                          ean, efc, ect, ehy, enh, ear, h0);
    ctab_kernel<<<1610, 256, 0, stream>>>(e_conj, e_arom, e_btype,
                                          e_bdir, e_bstereo, ctab5);

    // CSR build (re-run every call: ws is re-poisoned)
    hipMemsetAsync(cursor, 0, NN * sizeof(int), stream);
    count_kernel<<<2344, 256, 0, stream>>>(ei, cursor);
    btot_kernel<<<SBLK, 1024, 0, stream>>>(cursor, btot);
    bscan_kernel<<<1, 128, 0, stream>>>(btot, boff, rowstart);
    apply_kernel<<<SBLK, 1024, 0, stream>>>(cursor, boff, rowstart, cursor);
    fill_kernel<<<2344, 256, 0, stream>>>(ei, cursor, rec,
                                          econ, earo, ebt, ebd, ebs);

    for (int l = 0; l < LL; ++l) {
        gather_bn_kernel<<<6250, 256, 0, stream>>>(
            (l == 0) ? h0 : hpre, agg, rowstart, rec,
            ctab5 + (size_t)l * CTROWS * DD,
            (l == 0) ? idss : ss, (l == 0) ? 0 : 1);
        mlp_kernel<<<PBLK, 256, 0, stream>>>(
            agg, w1t + l * 32768, w2t + l * 32768,
            mlp_b1 + l * 256, mlp_b2 + l * 128,
            hpre, psum, psq, NN);
        reduce_kernel<<<128, 256, 0, stream>>>(
            psum, psq, bn_gamma + l * 128, bn_beta + l * 128, ss, PBLK);
    }
    final_bn_kernel<<<6250, 256, 0, stream>>>(hpre, (float*)d_out, ss);
}